// Round 1
// baseline (1755.100 us; speedup 1.0000x reference)
//
#include <hip/hip_runtime.h>

// GCN, 3 layers: 3 -> 32 -> 32 -> 1, N=100K nodes, E=6.4M edges + self loops.
// Strategy:
//  - deg via atomic counts over dst; dis = 1/sqrt(deg+1)
//  - L1: aggregate raw x (3-wide) then multiply by W1 (linearity of segsum)
//  - L2: aggregate h1' (32-wide, 32 lanes/edge, coalesced gather+atomics)
//  - L3: project p = h2'@W3 per node FIRST, aggregate scalars
//  - self-loop term v[i]*dis[i]^2 fused into node kernels (never in edge kernels)

#define BLK 256

__global__ void k_deg(const int* __restrict__ dst, float* __restrict__ deg, int E) {
    int t = blockIdx.x * blockDim.x + threadIdx.x;
    if (t < E) atomicAdd(&deg[dst[t]], 1.0f);
}

__global__ void k_dis(float* __restrict__ deg, float* __restrict__ dis, int N) {
    int i = blockIdx.x * blockDim.x + threadIdx.x;
    if (i < N) {
        float d = deg[i] + 1.0f;   // + self loop
        deg[i] = d;
        dis[i] = 1.0f / sqrtf(d);
    }
}

// Layer-1 edge aggregation of raw x (3 feats), 4 lanes per edge (lane 3 idle on atomic)
__global__ void k_agg_x(const int* __restrict__ src, const int* __restrict__ dst,
                        const float* __restrict__ x, const float* __restrict__ dis,
                        float* __restrict__ aggx, int E) {
    int t = blockIdx.x * blockDim.x + threadIdx.x;
    int e = t >> 2;
    int f = t & 3;
    if (e >= E) return;
    int s = src[e], d = dst[e];
    float nv = dis[s] * dis[d];
    if (f < 3) {
        atomicAdd(&aggx[d * 4 + f], x[s * 3 + f] * nv);
    }
}

// h1' = relu( (aggx + x*dis^2) @ W1 + b1 ), 32 lanes per node (j = output feat)
__global__ void k_node1(const float* __restrict__ x, const float* __restrict__ aggx,
                        const float* __restrict__ dis,
                        const float* __restrict__ W1, const float* __restrict__ b1,
                        float* __restrict__ h1, int N) {
    int t = blockIdx.x * blockDim.x + threadIdx.x;
    int i = t >> 5;
    int j = t & 31;
    if (i >= N) return;
    float di = dis[i];
    float invd = di * di;          // self-loop norm = dis[i]^2
    float acc = b1[j];
#pragma unroll
    for (int k = 0; k < 3; k++) {
        float a = aggx[i * 4 + k] + x[i * 3 + k] * invd;
        acc += a * W1[k * 32 + j];
    }
    h1[i * 32 + j] = fmaxf(acc, 0.0f);
}

// Layer-2 edge aggregation, 32 lanes per edge: agg1[dst][f] += h1[src][f]*norm
__global__ void k_agg_h(const int* __restrict__ src, const int* __restrict__ dst,
                        const float* __restrict__ h, const float* __restrict__ dis,
                        float* __restrict__ agg, int E) {
    int t = blockIdx.x * blockDim.x + threadIdx.x;
    int e = t >> 5;
    int f = t & 31;
    if (e >= E) return;
    int s = src[e], d = dst[e];
    float nv = dis[s] * dis[d];
    atomicAdd(&agg[d * 32 + f], h[s * 32 + f] * nv);
}

// h2' = relu( (agg1 + h1*dis^2) @ W2 + b2 );  p = h2' @ W3  (shuffle-reduced)
__global__ void k_node2(const float* __restrict__ h1, const float* __restrict__ agg1,
                        const float* __restrict__ dis,
                        const float* __restrict__ W2, const float* __restrict__ b2,
                        const float* __restrict__ W3,
                        float* __restrict__ p, int N) {
    int t = blockIdx.x * blockDim.x + threadIdx.x;
    int i = t >> 5;
    int j = t & 31;
    if (i >= N) return;
    float di = dis[i];
    float invd = di * di;
    // coalesced preload of this node's full-agg row element j
    float a = agg1[i * 32 + j] + h1[i * 32 + j] * invd;
    float acc = b2[j];
#pragma unroll
    for (int k = 0; k < 32; k++) {
        float ak = __shfl(a, k, 32);           // broadcast within 32-lane group
        acc += ak * W2[k * 32 + j];
    }
    float h2 = fmaxf(acc, 0.0f);
    float contrib = h2 * W3[j];
#pragma unroll
    for (int m = 16; m >= 1; m >>= 1)
        contrib += __shfl_xor(contrib, m, 32);
    if (j == 0) p[i] = contrib;
}

// Layer-3 edge aggregation of scalar p, 1 lane per edge
__global__ void k_agg_p(const int* __restrict__ src, const int* __restrict__ dst,
                        const float* __restrict__ p, const float* __restrict__ dis,
                        float* __restrict__ aggp, int E) {
    int e = blockIdx.x * blockDim.x + threadIdx.x;
    if (e >= E) return;
    int s = src[e], d = dst[e];
    atomicAdd(&aggp[d], p[s] * dis[s] * dis[d]);
}

__global__ void k_out(const float* __restrict__ aggp, const float* __restrict__ p,
                      const float* __restrict__ dis, const float* __restrict__ b3,
                      float* __restrict__ out, int N) {
    int i = blockIdx.x * blockDim.x + threadIdx.x;
    if (i < N) {
        float di = dis[i];
        out[i] = aggp[i] + p[i] * di * di + b3[0];
    }
}

extern "C" void kernel_launch(void* const* d_in, const int* in_sizes, int n_in,
                              void* d_out, int out_size, void* d_ws, size_t ws_size,
                              hipStream_t stream) {
    const float* x  = (const float*)d_in[0];
    const int*   ei = (const int*)d_in[1];
    const float* W1 = (const float*)d_in[2];
    const float* b1 = (const float*)d_in[3];
    const float* W2 = (const float*)d_in[4];
    const float* b2 = (const float*)d_in[5];
    const float* W3 = (const float*)d_in[6];
    const float* b3 = (const float*)d_in[7];
    float* out = (float*)d_out;

    int N = in_sizes[0] / 3;
    int E = in_sizes[1] / 2;
    const int* src = ei;
    const int* dst = ei + E;

    // workspace layout (floats): zeroed region first (deg|aggx|agg1|aggp = 38N)
    float* ws   = (float*)d_ws;
    float* deg  = ws;               // N
    float* aggx = deg  + N;         // 4N
    float* agg1 = aggx + 4 * N;     // 32N
    float* aggp = agg1 + 32 * N;    // N
    float* dis  = aggp + N;         // N   (written, not zeroed)
    float* h1   = dis  + N;         // 32N (written, not zeroed)
    float* p    = h1   + 32 * N;    // N   (written, not zeroed)

    hipMemsetAsync(ws, 0, (size_t)(38ll * N) * sizeof(float), stream);

    k_deg  <<<(E + BLK - 1) / BLK, BLK, 0, stream>>>(dst, deg, E);
    k_dis  <<<(N + BLK - 1) / BLK, BLK, 0, stream>>>(deg, dis, N);

    long long tx = (long long)E * 4;
    k_agg_x<<<(unsigned)((tx + BLK - 1) / BLK), BLK, 0, stream>>>(src, dst, x, dis, aggx, E);

    long long tn = (long long)N * 32;
    k_node1<<<(unsigned)((tn + BLK - 1) / BLK), BLK, 0, stream>>>(x, aggx, dis, W1, b1, h1, N);

    long long th = (long long)E * 32;
    k_agg_h<<<(unsigned)((th + BLK - 1) / BLK), BLK, 0, stream>>>(src, dst, h1, dis, agg1, E);

    k_node2<<<(unsigned)((tn + BLK - 1) / BLK), BLK, 0, stream>>>(h1, agg1, dis, W2, b2, W3, p, N);

    k_agg_p<<<(E + BLK - 1) / BLK, BLK, 0, stream>>>(src, dst, p, dis, aggp, E);

    k_out  <<<(N + BLK - 1) / BLK, BLK, 0, stream>>>(aggp, p, dis, b3, out, N);
}